// Round 1
// baseline (407.384 us; speedup 1.0000x reference)
//
#include <hip/hip_runtime.h>

// DLRM forward: bottom MLP -> embedding gather/pool -> pairwise interaction -> top MLP
// Shapes: T=26 tables, N=100000 rows, D=64; B=4096, L=32
// Bottom: 13->512->256->64 (ReLU each). Top: 415->512->256->1 (ReLU each).

constexpr int T_ = 26;
constexpr int N_ = 100000;
constexpr int D_ = 64;
constexpr int B_ = 4096;
constexpr int L_ = 32;
constexpr int NCAT = T_ + 1;          // 27
constexpr int NPAIR = NCAT * (NCAT - 1) / 2;  // 351
constexpr int RDIM = D_ + NPAIR;      // 415

// ---------------------------------------------------------------------------
// Tiled fp32 GEMM: C[M,N] = relu(A[M,K] @ W[N,K]^T + bias[N])
// BM=BN=64, BK=16, 256 threads, 4x4 micro-tile per thread.
// M, N assumed multiples of 64; K arbitrary (guarded).
// ---------------------------------------------------------------------------
template <int BM, int BN, int BK>
__global__ __launch_bounds__(256) void gemm_bias_relu(
    const float* __restrict__ A, const float* __restrict__ W,
    const float* __restrict__ bias, float* __restrict__ C,
    int M, int N, int K, int lda, int ldc)
{
    __shared__ float As[BK][BM + 4];   // +4 pad: keeps 16B alignment per row, spreads banks
    __shared__ float Ws[BK][BN + 4];

    const int m0 = blockIdx.x * BM;
    const int n0 = blockIdx.y * BN;
    const int tid = threadIdx.x;
    const int tx = tid % 16;
    const int ty = tid / 16;

    float acc[4][4] = {};

    for (int k0 = 0; k0 < K; k0 += BK) {
        // stage A tile (BM x BK), transposed into As[k][m]
        #pragma unroll
        for (int e = tid; e < BM * BK; e += 256) {
            int m = e / BK, k = e % BK;
            int kk = k0 + k;
            As[k][m] = (kk < K) ? A[(size_t)(m0 + m) * lda + kk] : 0.f;
        }
        // stage W tile (BN x BK), transposed into Ws[k][n]
        #pragma unroll
        for (int e = tid; e < BN * BK; e += 256) {
            int n = e / BK, k = e % BK;
            int kk = k0 + k;
            Ws[k][n] = (kk < K) ? W[(size_t)(n0 + n) * K + kk] : 0.f;
        }
        __syncthreads();

        #pragma unroll
        for (int k = 0; k < BK; ++k) {
            float4 a4 = *reinterpret_cast<const float4*>(&As[k][ty * 4]);
            float4 w4 = *reinterpret_cast<const float4*>(&Ws[k][tx * 4]);
            float av[4] = {a4.x, a4.y, a4.z, a4.w};
            float wv[4] = {w4.x, w4.y, w4.z, w4.w};
            #pragma unroll
            for (int i = 0; i < 4; ++i)
                #pragma unroll
                for (int j = 0; j < 4; ++j)
                    acc[i][j] = fmaf(av[i], wv[j], acc[i][j]);
        }
        __syncthreads();
    }

    #pragma unroll
    for (int i = 0; i < 4; ++i) {
        int row = m0 + ty * 4 + i;
        #pragma unroll
        for (int j = 0; j < 4; ++j) {
            int col = n0 + tx * 4 + j;
            float v = acc[i][j] + bias[col];
            C[(size_t)row * ldc + col] = fmaxf(v, 0.f);
        }
    }
}

// ---------------------------------------------------------------------------
// Embedding gather + pool: Tcat[b][1+t][d] = sum_l tables[t][idx[t,b,l]][d]
// One wave (64 threads) per (t,b) pair; lane = d.
// ---------------------------------------------------------------------------
__global__ __launch_bounds__(64) void gather_pool(
    const int* __restrict__ idx, const float* __restrict__ tables,
    float* __restrict__ Tcat)
{
    const int bid = blockIdx.x;          // 0 .. T_*B_-1
    const int t = bid / B_;
    const int b = bid % B_;
    const int d = threadIdx.x;

    const int* ip = idx + ((size_t)t * B_ + b) * L_;
    const float* tab = tables + (size_t)t * N_ * D_;

    // prefetch all indices (wave-uniform addresses -> broadcast loads)
    int rows[L_];
    #pragma unroll
    for (int l = 0; l < L_; ++l) rows[l] = ip[l];

    float s = 0.f;
    #pragma unroll
    for (int l = 0; l < L_; ++l)
        s += tab[(size_t)rows[l] * D_ + d];

    Tcat[((size_t)b * NCAT + 1 + t) * D_ + d] = s;
}

// ---------------------------------------------------------------------------
// Pairwise interaction: per batch element b,
//   R[b][0:64]     = Tcat[b][0][:]          (bottom-MLP output x)
//   R[b][64 + p]   = dot(Tcat[b][i], Tcat[b][j]),  p = i*(i-1)/2 + j, i>j
// One block of 128 threads per b; Tcat row block staged in LDS.
// ---------------------------------------------------------------------------
__global__ __launch_bounds__(128) void interact(
    const float* __restrict__ Tcat, float* __restrict__ R)
{
    const int b = blockIdx.x;
    __shared__ float tc[NCAT * D_];
    const int tid = threadIdx.x;

    for (int e = tid; e < NCAT * D_; e += 128)
        tc[e] = Tcat[(size_t)b * NCAT * D_ + e];
    __syncthreads();

    if (tid < D_) R[(size_t)b * RDIM + tid] = tc[tid];

    for (int p = tid; p < NPAIR; p += 128) {
        int i = (int)((1.0f + sqrtf(1.0f + 8.0f * (float)p)) * 0.5f);
        while (i * (i - 1) / 2 > p) --i;
        while ((i + 1) * i / 2 <= p) ++i;
        int j = p - i * (i - 1) / 2;
        const float* ri = &tc[i * D_];
        const float* rj = &tc[j * D_];
        float s = 0.f;
        #pragma unroll
        for (int d = 0; d < D_; ++d) s = fmaf(ri[d], rj[d], s);
        R[(size_t)b * RDIM + D_ + p] = s;
    }
}

// ---------------------------------------------------------------------------
// Final layer: out[b] = relu(dot(A[b], W[0]) + bias[0]), K=256, N=1
// One wave per row, 4 rows per 256-thread block.
// ---------------------------------------------------------------------------
__global__ __launch_bounds__(256) void final_layer(
    const float* __restrict__ A, const float* __restrict__ W,
    const float* __restrict__ bias, float* __restrict__ out)
{
    const int b = blockIdx.x * 4 + threadIdx.x / 64;
    const int lane = threadIdx.x % 64;
    const float* a = A + (size_t)b * 256;
    float s = 0.f;
    #pragma unroll
    for (int k = lane; k < 256; k += 64) s = fmaf(a[k], W[k], s);
    #pragma unroll
    for (int off = 32; off > 0; off >>= 1) s += __shfl_down(s, off);
    if (lane == 0) out[b] = fmaxf(s + bias[0], 0.f);
}

// ---------------------------------------------------------------------------

extern "C" void kernel_launch(void* const* d_in, const int* in_sizes, int n_in,
                              void* d_out, int out_size, void* d_ws, size_t ws_size,
                              hipStream_t stream)
{
    const float* dense_x = (const float*)d_in[0];
    const int*   indices = (const int*)d_in[1];
    const float* tables  = (const float*)d_in[2];
    const float* bot_W0  = (const float*)d_in[3];
    const float* bot_b0  = (const float*)d_in[4];
    const float* bot_W1  = (const float*)d_in[5];
    const float* bot_b1  = (const float*)d_in[6];
    const float* bot_W2  = (const float*)d_in[7];
    const float* bot_b2  = (const float*)d_in[8];
    const float* top_W0  = (const float*)d_in[9];
    const float* top_b0  = (const float*)d_in[10];
    const float* top_W1  = (const float*)d_in[11];
    const float* top_b1  = (const float*)d_in[12];
    const float* top_W2  = (const float*)d_in[13];
    const float* top_b2  = (const float*)d_in[14];
    float* out = (float*)d_out;

    // workspace layout (floats)
    float* ws = (float*)d_ws;
    float* buf1 = ws;                       // 4096*512 = 2,097,152
    float* buf2 = buf1 + (size_t)B_ * 512;  // 4096*256 = 1,048,576
    float* tcat = buf2 + (size_t)B_ * 256;  // 4096*27*64 = 7,077,888
    float* Rbuf = tcat + (size_t)B_ * NCAT * D_;  // 4096*415 = 1,699,840

    // bottom MLP
    gemm_bias_relu<64, 64, 16><<<dim3(B_ / 64, 512 / 64), 256, 0, stream>>>(
        dense_x, bot_W0, bot_b0, buf1, B_, 512, 13, 13, 512);
    gemm_bias_relu<64, 64, 16><<<dim3(B_ / 64, 256 / 64), 256, 0, stream>>>(
        buf1, bot_W1, bot_b1, buf2, B_, 256, 512, 512, 256);
    // final bottom layer writes x directly into Tcat[b][0][:]
    gemm_bias_relu<64, 64, 16><<<dim3(B_ / 64, 64 / 64), 256, 0, stream>>>(
        buf2, bot_W2, bot_b2, tcat, B_, 64, 256, 256, NCAT * D_);

    // embedding gather + pool into Tcat[b][1+t][:]
    gather_pool<<<T_ * B_, 64, 0, stream>>>(indices, tables, tcat);

    // pairwise interaction -> R
    interact<<<B_, 128, 0, stream>>>(tcat, Rbuf);

    // top MLP
    gemm_bias_relu<64, 64, 16><<<dim3(B_ / 64, 512 / 64), 256, 0, stream>>>(
        Rbuf, top_W0, top_b0, buf1, B_, 512, RDIM, RDIM, 512);
    gemm_bias_relu<64, 64, 16><<<dim3(B_ / 64, 256 / 64), 256, 0, stream>>>(
        buf1, top_W1, top_b1, buf2, B_, 256, 512, 512, 256);
    final_layer<<<B_ / 4, 256, 0, stream>>>(buf2, top_W2, top_b2, out);
}

// Round 2
// 284.527 us; speedup vs baseline: 1.4318x; 1.4318x over previous
//
#include <hip/hip_runtime.h>

// DLRM forward: bottom MLP -> embedding gather/pool -> pairwise interaction -> top MLP
// T=26 tables, N=100000 rows, D=64; B=4096, L=32
// Bottom: 13->512->256->64 (ReLU). Top: 415->512->256->1 (ReLU).

constexpr int T_ = 26;
constexpr int N_ = 100000;
constexpr int D_ = 64;
constexpr int B_ = 4096;
constexpr int L_ = 32;
constexpr int NCAT = T_ + 1;                 // 27
constexpr int NPAIR = NCAT * (NCAT - 1) / 2; // 351
constexpr int RDIM = D_ + NPAIR;             // 415

// ---------------------------------------------------------------------------
// Fused GEMM (no split): C = relu(A[M,K] @ W[N,K]^T + bias). Used for K=13 layer.
// ---------------------------------------------------------------------------
template <int BM, int BN, int BK>
__global__ __launch_bounds__(256) void gemm_bias_relu(
    const float* __restrict__ A, const float* __restrict__ W,
    const float* __restrict__ bias, float* __restrict__ C,
    int M, int N, int K, int lda, int ldc)
{
    __shared__ float As[BK][BM + 4];
    __shared__ float Ws[BK][BN + 4];

    const int m0 = blockIdx.x * BM;
    const int n0 = blockIdx.y * BN;
    const int tid = threadIdx.x;
    const int tx = tid % 16;
    const int ty = tid / 16;

    float acc[4][4] = {};

    for (int k0 = 0; k0 < K; k0 += BK) {
        #pragma unroll
        for (int e = tid; e < BM * BK; e += 256) {
            int m = e / BK, k = e % BK;
            int kk = k0 + k;
            As[k][m] = (kk < K) ? A[(size_t)(m0 + m) * lda + kk] : 0.f;
        }
        #pragma unroll
        for (int e = tid; e < BN * BK; e += 256) {
            int n = e / BK, k = e % BK;
            int kk = k0 + k;
            Ws[k][n] = (kk < K) ? W[(size_t)(n0 + n) * K + kk] : 0.f;
        }
        __syncthreads();

        #pragma unroll
        for (int k = 0; k < BK; ++k) {
            float4 a4 = *reinterpret_cast<const float4*>(&As[k][ty * 4]);
            float4 w4 = *reinterpret_cast<const float4*>(&Ws[k][tx * 4]);
            float av[4] = {a4.x, a4.y, a4.z, a4.w};
            float wv[4] = {w4.x, w4.y, w4.z, w4.w};
            #pragma unroll
            for (int i = 0; i < 4; ++i)
                #pragma unroll
                for (int j = 0; j < 4; ++j)
                    acc[i][j] = fmaf(av[i], wv[j], acc[i][j]);
        }
        __syncthreads();
    }

    #pragma unroll
    for (int i = 0; i < 4; ++i) {
        int row = m0 + ty * 4 + i;
        #pragma unroll
        for (int j = 0; j < 4; ++j) {
            int col = n0 + tx * 4 + j;
            float v = acc[i][j] + bias[col];
            C[(size_t)row * ldc + col] = fmaxf(v, 0.f);
        }
    }
}

// ---------------------------------------------------------------------------
// Split-K GEMM: part[s][M][N] = A[:, ks:ke] @ W[:, ks:ke]^T  (no bias/relu)
// grid = (M/BM, N/BN, S). Raises grid 2-8x so occupancy reaches 4 waves/SIMD.
// ---------------------------------------------------------------------------
template <int BM, int BN, int BK>
__global__ __launch_bounds__(256) void gemm_splitk(
    const float* __restrict__ A, const float* __restrict__ W,
    float* __restrict__ part, int M, int N, int K, int lda, int S)
{
    __shared__ float As[BK][BM + 4];
    __shared__ float Ws[BK][BN + 4];

    const int m0 = blockIdx.x * BM;
    const int n0 = blockIdx.y * BN;
    const int s  = blockIdx.z;
    const int Kc = (K + S - 1) / S;
    const int kbeg = s * Kc;
    const int kend = min(K, kbeg + Kc);

    const int tid = threadIdx.x;
    const int tx = tid % 16;
    const int ty = tid / 16;

    float acc[4][4] = {};

    for (int k0 = kbeg; k0 < kend; k0 += BK) {
        #pragma unroll
        for (int e = tid; e < BM * BK; e += 256) {
            int m = e / BK, k = e % BK;
            int kk = k0 + k;
            As[k][m] = (kk < kend) ? A[(size_t)(m0 + m) * lda + kk] : 0.f;
        }
        #pragma unroll
        for (int e = tid; e < BN * BK; e += 256) {
            int n = e / BK, k = e % BK;
            int kk = k0 + k;
            Ws[k][n] = (kk < kend) ? W[(size_t)(n0 + n) * K + kk] : 0.f;
        }
        __syncthreads();

        #pragma unroll
        for (int k = 0; k < BK; ++k) {
            float4 a4 = *reinterpret_cast<const float4*>(&As[k][ty * 4]);
            float4 w4 = *reinterpret_cast<const float4*>(&Ws[k][tx * 4]);
            float av[4] = {a4.x, a4.y, a4.z, a4.w};
            float wv[4] = {w4.x, w4.y, w4.z, w4.w};
            #pragma unroll
            for (int i = 0; i < 4; ++i)
                #pragma unroll
                for (int j = 0; j < 4; ++j)
                    acc[i][j] = fmaf(av[i], wv[j], acc[i][j]);
        }
        __syncthreads();
    }

    #pragma unroll
    for (int i = 0; i < 4; ++i) {
        size_t row = (size_t)s * M + m0 + ty * 4 + i;
        #pragma unroll
        for (int j = 0; j < 4; ++j)
            part[row * N + n0 + tx * 4 + j] = acc[i][j];
    }
}

// combine split-K partials: C[m][n] = relu(sum_s part[s][m][n] + bias[n])
__global__ __launch_bounds__(256) void combine_bias_relu(
    const float* __restrict__ part, const float* __restrict__ bias,
    float* __restrict__ C, int M, int N, int ldc, int S)
{
    int idx = blockIdx.x * 256 + threadIdx.x;
    int i = idx * 4;
    if (i >= M * N) return;
    int m = i / N;
    int n = i % N;

    float4 acc = *reinterpret_cast<const float4*>(&part[(size_t)m * N + n]);
    for (int s = 1; s < S; ++s) {
        float4 p = *reinterpret_cast<const float4*>(&part[((size_t)s * M + m) * N + n]);
        acc.x += p.x; acc.y += p.y; acc.z += p.z; acc.w += p.w;
    }
    float4 bi = *reinterpret_cast<const float4*>(&bias[n]);
    acc.x = fmaxf(acc.x + bi.x, 0.f);
    acc.y = fmaxf(acc.y + bi.y, 0.f);
    acc.z = fmaxf(acc.z + bi.z, 0.f);
    acc.w = fmaxf(acc.w + bi.w, 0.f);
    *reinterpret_cast<float4*>(&C[(size_t)m * ldc + n]) = acc;
}

// ---------------------------------------------------------------------------
// Embedding gather + pool: Tcat[b][1+t][d] = sum_l tables[t][idx[t,b,l]][d]
// One wave per (t,b); lane = d. Consecutive blocks share a table -> L3 locality.
// ---------------------------------------------------------------------------
__global__ __launch_bounds__(64) void gather_pool(
    const int* __restrict__ idx, const float* __restrict__ tables,
    float* __restrict__ Tcat)
{
    const int bid = blockIdx.x;
    const int t = bid / B_;
    const int b = bid % B_;
    const int d = threadIdx.x;

    const int* ip = idx + ((size_t)t * B_ + b) * L_;
    const float* tab = tables + (size_t)t * N_ * D_;

    int rows[L_];
    #pragma unroll
    for (int l = 0; l < L_; ++l) rows[l] = ip[l];

    float s = 0.f;
    #pragma unroll
    for (int l = 0; l < L_; ++l)
        s += tab[(size_t)rows[l] * D_ + d];

    Tcat[((size_t)b * NCAT + 1 + t) * D_ + d] = s;
}

// ---------------------------------------------------------------------------
// Pairwise interaction. LDS stored TRANSPOSED with stride 29 (coprime to 32
// banks): tc[d*29+i]. At fixed d, lanes read distinct i/j -> distinct banks
// (vs. old layout: 32-way conflict, ~11x LDS penalty).
// ---------------------------------------------------------------------------
__global__ __launch_bounds__(128) void interact(
    const float* __restrict__ Tcat, float* __restrict__ R)
{
    const int b = blockIdx.x;
    __shared__ float tc[D_ * 29];
    const int tid = threadIdx.x;

    for (int e = tid; e < NCAT * D_; e += 128) {
        int i = e / D_, d = e % D_;
        tc[d * 29 + i] = Tcat[(size_t)b * NCAT * D_ + e];
    }
    __syncthreads();

    if (tid < D_) R[(size_t)b * RDIM + tid] = Tcat[(size_t)b * NCAT * D_ + tid];

    for (int p = tid; p < NPAIR; p += 128) {
        int i = (int)((1.0f + sqrtf(1.0f + 8.0f * (float)p)) * 0.5f);
        while (i * (i - 1) / 2 > p) --i;
        while ((i + 1) * i / 2 <= p) ++i;
        int j = p - i * (i - 1) / 2;
        float s = 0.f;
        #pragma unroll
        for (int d = 0; d < D_; ++d)
            s = fmaf(tc[d * 29 + i], tc[d * 29 + j], s);
        R[(size_t)b * RDIM + D_ + p] = s;
    }
}

// ---------------------------------------------------------------------------
// Final layer: out[b] = relu(dot(A[b], W[0]) + bias[0]), K=256
// ---------------------------------------------------------------------------
__global__ __launch_bounds__(256) void final_layer(
    const float* __restrict__ A, const float* __restrict__ W,
    const float* __restrict__ bias, float* __restrict__ out)
{
    const int b = blockIdx.x * 4 + threadIdx.x / 64;
    const int lane = threadIdx.x % 64;
    const float* a = A + (size_t)b * 256;
    float s = 0.f;
    #pragma unroll
    for (int k = lane; k < 256; k += 64) s = fmaf(a[k], W[k], s);
    #pragma unroll
    for (int off = 32; off > 0; off >>= 1) s += __shfl_down(s, off);
    if (lane == 0) out[b] = fmaxf(s + bias[0], 0.f);
}

// ---------------------------------------------------------------------------

extern "C" void kernel_launch(void* const* d_in, const int* in_sizes, int n_in,
                              void* d_out, int out_size, void* d_ws, size_t ws_size,
                              hipStream_t stream)
{
    const float* dense_x = (const float*)d_in[0];
    const int*   indices = (const int*)d_in[1];
    const float* tables  = (const float*)d_in[2];
    const float* bot_W0  = (const float*)d_in[3];
    const float* bot_b0  = (const float*)d_in[4];
    const float* bot_W1  = (const float*)d_in[5];
    const float* bot_b1  = (const float*)d_in[6];
    const float* bot_W2  = (const float*)d_in[7];
    const float* bot_b2  = (const float*)d_in[8];
    const float* top_W0  = (const float*)d_in[9];
    const float* top_b0  = (const float*)d_in[10];
    const float* top_W1  = (const float*)d_in[11];
    const float* top_b1  = (const float*)d_in[12];
    const float* top_W2  = (const float*)d_in[13];
    const float* top_b2  = (const float*)d_in[14];
    float* out = (float*)d_out;

    // workspace layout (floats)
    float* ws = (float*)d_ws;
    float* buf1 = ws;                             // 4096*512
    float* buf2 = buf1 + (size_t)B_ * 512;        // 4096*256
    float* tcat = buf2 + (size_t)B_ * 256;        // 4096*27*64
    float* Rbuf = tcat + (size_t)B_ * NCAT * D_;  // 4096*415
    float* part = Rbuf + (size_t)B_ * RDIM;       // up to 4*4096*512

    // ---- bottom MLP ----
    // layer 0: K=13 (one BK step), fused epilogue. grid 512.
    gemm_bias_relu<64, 64, 16><<<dim3(B_ / 64, 512 / 64), 256, 0, stream>>>(
        dense_x, bot_W0, bot_b0, buf1, B_, 512, 13, 13, 512);

    // layer 1: 4096x256, K=512. split-K 4 -> 1024 blocks.
    gemm_splitk<64, 64, 32><<<dim3(B_ / 64, 256 / 64, 4), 256, 0, stream>>>(
        buf1, bot_W1, part, B_, 256, 512, 512, 4);
    combine_bias_relu<<<(B_ * 256 / 4 + 255) / 256, 256, 0, stream>>>(
        part, bot_b1, buf2, B_, 256, 256, 4);

    // layer 2: 4096x64, K=256. split-K 8 -> 512 blocks. Writes x into Tcat[b][0][:].
    gemm_splitk<64, 64, 32><<<dim3(B_ / 64, 64 / 64, 8), 256, 0, stream>>>(
        buf2, bot_W2, part, B_, 64, 256, 256, 8);
    combine_bias_relu<<<(B_ * 64 / 4 + 255) / 256, 256, 0, stream>>>(
        part, bot_b2, tcat, B_, 64, NCAT * D_, 8);

    // ---- embedding gather + pool ----
    gather_pool<<<T_ * B_, 64, 0, stream>>>(indices, tables, tcat);

    // ---- pairwise interaction ----
    interact<<<B_, 128, 0, stream>>>(tcat, Rbuf);

    // ---- top MLP ----
    // layer 0: 4096x512, K=415. split-K 2 -> 1024 blocks.
    gemm_splitk<64, 64, 32><<<dim3(B_ / 64, 512 / 64, 2), 256, 0, stream>>>(
        Rbuf, top_W0, part, B_, 512, RDIM, RDIM, 2);
    combine_bias_relu<<<(B_ * 512 / 4 + 255) / 256, 256, 0, stream>>>(
        part, top_b0, buf1, B_, 512, 512, 2);

    // layer 1: 4096x256, K=512. split-K 4 -> 1024 blocks.
    gemm_splitk<64, 64, 32><<<dim3(B_ / 64, 256 / 64, 4), 256, 0, stream>>>(
        buf1, top_W1, part, B_, 256, 512, 512, 4);
    combine_bias_relu<<<(B_ * 256 / 4 + 255) / 256, 256, 0, stream>>>(
        part, top_b1, buf2, B_, 256, 256, 4);

    // layer 2: K=256 -> scalar output
    final_layer<<<B_ / 4, 256, 0, stream>>>(buf2, top_W2, top_b2, out);
}

// Round 3
// 206.689 us; speedup vs baseline: 1.9710x; 1.3766x over previous
//
#include <hip/hip_runtime.h>
#include <hip/hip_bf16.h>

// DLRM forward. Bottom/top MLP GEMMs run on MFMA via bf16x3 split emulation
// (x = hi+lo bf16; x*w = hh + hl + lh, fp32 accumulate; rel err ~3e-5).
// T=26, N=100000, D=64; B=4096, L=32.

constexpr int T_ = 26;
constexpr int N_ = 100000;
constexpr int D_ = 64;
constexpr int B_ = 4096;
constexpr int L_ = 32;
constexpr int NCAT = T_ + 1;                 // 27
constexpr int NPAIR = NCAT * (NCAT - 1) / 2; // 351
constexpr int RDIM = D_ + NPAIR;             // 415
constexpr int RPAD = 448;                    // 415 padded to x64 for MFMA K-loop

using bf16x8 = __attribute__((ext_vector_type(8))) short;
using f32x4  = __attribute__((ext_vector_type(4))) float;

__device__ __forceinline__ void split_bf16(float v, ushort& h, ushort& l) {
    __hip_bfloat16 hb = __float2bfloat16(v);
    float hf = __bfloat162float(hb);
    __hip_bfloat16 lb = __float2bfloat16(v - hf);
    h = __builtin_bit_cast(ushort, hb);
    l = __builtin_bit_cast(ushort, lb);
}

// ---------------------------------------------------------------------------
// Weight split: W fp32 [N][K] -> hi/lo bf16 [N][Kp], pad cols zeroed.
// ---------------------------------------------------------------------------
__global__ __launch_bounds__(256) void convert_split(
    const float* __restrict__ W, ushort* __restrict__ hi, ushort* __restrict__ lo,
    int N, int K, int Kp)
{
    int idx = blockIdx.x * 256 + threadIdx.x;
    if (idx >= N * Kp) return;
    int n = idx / Kp, k = idx % Kp;
    ushort h = 0, l = 0;
    if (k < K) split_bf16(W[(size_t)n * K + k], h, l);
    hi[idx] = h; lo[idx] = l;
}

// ---------------------------------------------------------------------------
// MFMA GEMM, bf16x3: C = relu(A @ W^T + bias).
// A: [M][lda] split bf16 (Ah, Al); W: [N][ldw] split bf16.
// BM=BN=64, BK=64, 256 threads = 4 waves (2x2), 32x32 per wave (2x2 frags).
// LDS tiles XOR-swizzled on 16B slots (slot ^= row&7) -> conflict-even b128.
// EPI: 0 = fp32 C[ldc], 1 = split bf16 Ch/Cl[ldc].
// K, lda, ldw multiples of 64; M, N multiples of 64.
// ---------------------------------------------------------------------------
template <int EPI>
__global__ __launch_bounds__(256) void gemm_mfma_x3(
    const ushort* __restrict__ Ah, const ushort* __restrict__ Al,
    const ushort* __restrict__ Wh, const ushort* __restrict__ Wl,
    const float* __restrict__ bias,
    float* __restrict__ Cf, ushort* __restrict__ Ch, ushort* __restrict__ Cl,
    int K, int lda, int ldw, int ldc)
{
    __shared__ ushort smAh[64 * 64], smAl[64 * 64], smWh[64 * 64], smWl[64 * 64];

    const int m0 = blockIdx.x * 64;
    const int n0 = blockIdx.y * 64;
    const int tid = threadIdx.x;
    const int l = tid & 63;
    const int w = tid >> 6;
    const int wm = w >> 1, wn = w & 1;

    f32x4 acc[2][2] = {};

    // staging coords: 512 chunks of 16B per tile; 2 chunks/thread
    const int r0 = tid >> 3, s0 = tid & 7;          // chunk tid
    const int r1 = (tid + 256) >> 3, s1 = tid & 7;  // chunk tid+256

    for (int k0 = 0; k0 < K; k0 += 64) {
        // stage 4 tiles
        {
            const int4* gAh0 = (const int4*)(Ah + (size_t)(m0 + r0) * lda + k0 + s0 * 8);
            const int4* gAh1 = (const int4*)(Ah + (size_t)(m0 + r1) * lda + k0 + s1 * 8);
            const int4* gAl0 = (const int4*)(Al + (size_t)(m0 + r0) * lda + k0 + s0 * 8);
            const int4* gAl1 = (const int4*)(Al + (size_t)(m0 + r1) * lda + k0 + s1 * 8);
            const int4* gWh0 = (const int4*)(Wh + (size_t)(n0 + r0) * ldw + k0 + s0 * 8);
            const int4* gWh1 = (const int4*)(Wh + (size_t)(n0 + r1) * ldw + k0 + s1 * 8);
            const int4* gWl0 = (const int4*)(Wl + (size_t)(n0 + r0) * ldw + k0 + s0 * 8);
            const int4* gWl1 = (const int4*)(Wl + (size_t)(n0 + r1) * ldw + k0 + s1 * 8);
            int d0 = r0 * 64 + ((s0 ^ (r0 & 7)) * 8);
            int d1 = r1 * 64 + ((s1 ^ (r1 & 7)) * 8);
            *(int4*)&smAh[d0] = *gAh0;  *(int4*)&smAh[d1] = *gAh1;
            *(int4*)&smAl[d0] = *gAl0;  *(int4*)&smAl[d1] = *gAl1;
            *(int4*)&smWh[d0] = *gWh0;  *(int4*)&smWh[d1] = *gWh1;
            *(int4*)&smWl[d0] = *gWl0;  *(int4*)&smWl[d1] = *gWl1;
        }
        __syncthreads();

        #pragma unroll
        for (int ks = 0; ks < 2; ++ks) {
            bf16x8 ah[2], al[2], bh[2], bl[2];
            #pragma unroll
            for (int fm = 0; fm < 2; ++fm) {
                int ar = wm * 32 + fm * 16 + (l & 15);
                int slot = (ks * 4 + (l >> 4)) ^ (ar & 7);
                ah[fm] = *(const bf16x8*)&smAh[ar * 64 + slot * 8];
                al[fm] = *(const bf16x8*)&smAl[ar * 64 + slot * 8];
            }
            #pragma unroll
            for (int fn = 0; fn < 2; ++fn) {
                int wr = wn * 32 + fn * 16 + (l & 15);
                int slot = (ks * 4 + (l >> 4)) ^ (wr & 7);
                bh[fn] = *(const bf16x8*)&smWh[wr * 64 + slot * 8];
                bl[fn] = *(const bf16x8*)&smWl[wr * 64 + slot * 8];
            }
            #pragma unroll
            for (int fm = 0; fm < 2; ++fm)
                #pragma unroll
                for (int fn = 0; fn < 2; ++fn) {
                    acc[fm][fn] = __builtin_amdgcn_mfma_f32_16x16x32_bf16(ah[fm], bh[fn], acc[fm][fn], 0, 0, 0);
                    acc[fm][fn] = __builtin_amdgcn_mfma_f32_16x16x32_bf16(ah[fm], bl[fn], acc[fm][fn], 0, 0, 0);
                    acc[fm][fn] = __builtin_amdgcn_mfma_f32_16x16x32_bf16(al[fm], bh[fn], acc[fm][fn], 0, 0, 0);
                }
        }
        __syncthreads();
    }

    // epilogue: C/D frag mapping col = l&15, row = (l>>4)*4 + j  [m89]
    #pragma unroll
    for (int fm = 0; fm < 2; ++fm)
        #pragma unroll
        for (int fn = 0; fn < 2; ++fn) {
            int gcol = n0 + wn * 32 + fn * 16 + (l & 15);
            float bv = bias[gcol];
            #pragma unroll
            for (int j = 0; j < 4; ++j) {
                int grow = m0 + wm * 32 + fm * 16 + (l >> 4) * 4 + j;
                float v = fmaxf(acc[fm][fn][j] + bv, 0.f);
                if (EPI == 0) {
                    Cf[(size_t)grow * ldc + gcol] = v;
                } else {
                    ushort h, lo_;
                    split_bf16(v, h, lo_);
                    Ch[(size_t)grow * ldc + gcol] = h;
                    Cl[(size_t)grow * ldc + gcol] = lo_;
                }
            }
        }
}

// ---------------------------------------------------------------------------
// Bottom layer 0 (K=13): fp32 vector GEMM, epilogue writes split bf16.
// ---------------------------------------------------------------------------
__global__ __launch_bounds__(256) void gemm13_split(
    const float* __restrict__ A, const float* __restrict__ W,
    const float* __restrict__ bias, ushort* __restrict__ Ch, ushort* __restrict__ Cl,
    int ldc)
{
    constexpr int K = 13;
    __shared__ float As[K][64 + 4];
    __shared__ float Ws[K][64 + 4];

    const int m0 = blockIdx.x * 64;
    const int n0 = blockIdx.y * 64;
    const int tid = threadIdx.x;
    const int tx = tid % 16;
    const int ty = tid / 16;

    for (int e = tid; e < 64 * K; e += 256) {
        int m = e / K, k = e % K;
        As[k][m] = A[(size_t)(m0 + m) * K + k];
        Ws[k][m] = W[(size_t)(n0 + m) * K + k];
    }
    __syncthreads();

    float acc[4][4] = {};
    #pragma unroll
    for (int k = 0; k < K; ++k) {
        float4 a4 = *reinterpret_cast<const float4*>(&As[k][ty * 4]);
        float4 w4 = *reinterpret_cast<const float4*>(&Ws[k][tx * 4]);
        float av[4] = {a4.x, a4.y, a4.z, a4.w};
        float wv[4] = {w4.x, w4.y, w4.z, w4.w};
        #pragma unroll
        for (int i = 0; i < 4; ++i)
            #pragma unroll
            for (int j = 0; j < 4; ++j)
                acc[i][j] = fmaf(av[i], wv[j], acc[i][j]);
    }

    #pragma unroll
    for (int i = 0; i < 4; ++i) {
        int row = m0 + ty * 4 + i;
        #pragma unroll
        for (int j = 0; j < 4; ++j) {
            int col = n0 + tx * 4 + j;
            float v = fmaxf(acc[i][j] + bias[col], 0.f);
            ushort h, lo_;
            split_bf16(v, h, lo_);
            Ch[(size_t)row * ldc + col] = h;
            Cl[(size_t)row * ldc + col] = lo_;
        }
    }
}

// ---------------------------------------------------------------------------
// Embedding gather + pool: Tcat[b][1+t][d] = sum_l tables[t][idx[t,b,l]][d]
// ---------------------------------------------------------------------------
__global__ __launch_bounds__(64) void gather_pool(
    const int* __restrict__ idx, const float* __restrict__ tables,
    float* __restrict__ Tcat)
{
    const int bid = blockIdx.x;
    const int t = bid / B_;
    const int b = bid % B_;
    const int d = threadIdx.x;

    const int* ip = idx + ((size_t)t * B_ + b) * L_;
    const float* tab = tables + (size_t)t * N_ * D_;

    int rows[L_];
    #pragma unroll
    for (int l = 0; l < L_; ++l) rows[l] = ip[l];

    float s = 0.f;
    #pragma unroll
    for (int l = 0; l < L_; ++l)
        s += tab[(size_t)rows[l] * D_ + d];

    Tcat[((size_t)b * NCAT + 1 + t) * D_ + d] = s;
}

// ---------------------------------------------------------------------------
// Pairwise interaction -> R in split bf16, padded to RPAD with zeros.
// LDS transposed stride-29 (coprime with 32 banks) -> conflict-free dot loop.
// ---------------------------------------------------------------------------
__global__ __launch_bounds__(128) void interact_split(
    const float* __restrict__ Tcat, ushort* __restrict__ Rh, ushort* __restrict__ Rl)
{
    const int b = blockIdx.x;
    __shared__ float tc[D_ * 29];
    const int tid = threadIdx.x;

    for (int e = tid; e < NCAT * D_; e += 128) {
        int i = e / D_, d = e % D_;
        tc[d * 29 + i] = Tcat[(size_t)b * NCAT * D_ + e];
    }
    __syncthreads();

    if (tid < D_) {
        ushort h, lo_;
        split_bf16(Tcat[(size_t)b * NCAT * D_ + tid], h, lo_);
        Rh[(size_t)b * RPAD + tid] = h;
        Rl[(size_t)b * RPAD + tid] = lo_;
    }
    if (tid < RPAD - RDIM) {  // zero pad cols 415..447
        Rh[(size_t)b * RPAD + RDIM + tid] = 0;
        Rl[(size_t)b * RPAD + RDIM + tid] = 0;
    }

    for (int p = tid; p < NPAIR; p += 128) {
        int i = (int)((1.0f + sqrtf(1.0f + 8.0f * (float)p)) * 0.5f);
        while (i * (i - 1) / 2 > p) --i;
        while ((i + 1) * i / 2 <= p) ++i;
        int j = p - i * (i - 1) / 2;
        float s = 0.f;
        #pragma unroll
        for (int d = 0; d < D_; ++d)
            s = fmaf(tc[d * 29 + i], tc[d * 29 + j], s);
        ushort h, lo_;
        split_bf16(s, h, lo_);
        Rh[(size_t)b * RPAD + D_ + p] = h;
        Rl[(size_t)b * RPAD + D_ + p] = lo_;
    }
}

// ---------------------------------------------------------------------------
// Final layer: out[b] = relu(dot(A[b], W[0]) + bias[0]), K=256 fp32
// ---------------------------------------------------------------------------
__global__ __launch_bounds__(256) void final_layer(
    const float* __restrict__ A, const float* __restrict__ W,
    const float* __restrict__ bias, float* __restrict__ out)
{
    const int b = blockIdx.x * 4 + threadIdx.x / 64;
    const int lane = threadIdx.x % 64;
    const float* a = A + (size_t)b * 256;
    float s = 0.f;
    #pragma unroll
    for (int k = lane; k < 256; k += 64) s = fmaf(a[k], W[k], s);
    #pragma unroll
    for (int off = 32; off > 0; off >>= 1) s += __shfl_down(s, off);
    if (lane == 0) out[b] = fmaxf(s + bias[0], 0.f);
}

// ---------------------------------------------------------------------------

extern "C" void kernel_launch(void* const* d_in, const int* in_sizes, int n_in,
                              void* d_out, int out_size, void* d_ws, size_t ws_size,
                              hipStream_t stream)
{
    const float* dense_x = (const float*)d_in[0];
    const int*   indices = (const int*)d_in[1];
    const float* tables  = (const float*)d_in[2];
    const float* bot_W0  = (const float*)d_in[3];
    const float* bot_b0  = (const float*)d_in[4];
    const float* bot_W1  = (const float*)d_in[5];
    const float* bot_b1  = (const float*)d_in[6];
    const float* bot_W2  = (const float*)d_in[7];
    const float* bot_b2  = (const float*)d_in[8];
    const float* top_W0  = (const float*)d_in[9];
    const float* top_b0  = (const float*)d_in[10];
    const float* top_W1  = (const float*)d_in[11];
    const float* top_b1  = (const float*)d_in[12];
    const float* top_W2  = (const float*)d_in[13];
    const float* top_b2  = (const float*)d_in[14];
    float* out = (float*)d_out;

    // workspace layout (256B-aligned regions)
    char* base = (char*)d_ws;
    size_t off = 0;
    auto alloc = [&](size_t bytes) { char* p = base + off; off = (off + bytes + 255) & ~(size_t)255; return p; };
    float*  tcat  = (float*) alloc((size_t)B_ * NCAT * D_ * 4);   // 28.3 MB
    float*  buf2f = (float*) alloc((size_t)B_ * 256 * 4);         // 4 MB
    ushort* b1h   = (ushort*)alloc((size_t)B_ * 512 * 2);         // 4 MB
    ushort* b1l   = (ushort*)alloc((size_t)B_ * 512 * 2);
    ushort* b2h   = (ushort*)alloc((size_t)B_ * 256 * 2);         // 2 MB
    ushort* b2l   = (ushort*)alloc((size_t)B_ * 256 * 2);
    ushort* Rh    = (ushort*)alloc((size_t)B_ * RPAD * 2);        // 3.7 MB
    ushort* Rl    = (ushort*)alloc((size_t)B_ * RPAD * 2);
    ushort* wb1h  = (ushort*)alloc((size_t)256 * 512 * 2);
    ushort* wb1l  = (ushort*)alloc((size_t)256 * 512 * 2);
    ushort* wb2h  = (ushort*)alloc((size_t)64 * 256 * 2);
    ushort* wb2l  = (ushort*)alloc((size_t)64 * 256 * 2);
    ushort* wt0h  = (ushort*)alloc((size_t)512 * RPAD * 2);
    ushort* wt0l  = (ushort*)alloc((size_t)512 * RPAD * 2);
    ushort* wt1h  = (ushort*)alloc((size_t)256 * 512 * 2);
    ushort* wt1l  = (ushort*)alloc((size_t)256 * 512 * 2);

    // weight splits
    convert_split<<<(256 * 512 + 255) / 256, 256, 0, stream>>>(bot_W1, wb1h, wb1l, 256, 512, 512);
    convert_split<<<(64 * 256 + 255) / 256, 256, 0, stream>>>(bot_W2, wb2h, wb2l, 64, 256, 256);
    convert_split<<<(512 * RPAD + 255) / 256, 256, 0, stream>>>(top_W0, wt0h, wt0l, 512, RDIM, RPAD);
    convert_split<<<(256 * 512 + 255) / 256, 256, 0, stream>>>(top_W1, wt1h, wt1l, 256, 512, 512);

    // bottom MLP
    gemm13_split<<<dim3(B_ / 64, 512 / 64), 256, 0, stream>>>(
        dense_x, bot_W0, bot_b0, b1h, b1l, 512);
    gemm_mfma_x3<1><<<dim3(B_ / 64, 256 / 64), 256, 0, stream>>>(
        b1h, b1l, wb1h, wb1l, bot_b1, nullptr, b2h, b2l, 512, 512, 512, 256);
    gemm_mfma_x3<0><<<dim3(B_ / 64, 64 / 64), 256, 0, stream>>>(
        b2h, b2l, wb2h, wb2l, bot_b2, tcat, nullptr, nullptr, 256, 256, 256, NCAT * D_);

    // embedding gather + pool
    gather_pool<<<T_ * B_, 64, 0, stream>>>(indices, tables, tcat);

    // interaction -> split R
    interact_split<<<B_, 128, 0, stream>>>(tcat, Rh, Rl);

    // top MLP
    gemm_mfma_x3<1><<<dim3(B_ / 64, 512 / 64), 256, 0, stream>>>(
        Rh, Rl, wt0h, wt0l, top_b0, nullptr, b1h, b1l, RPAD, RPAD, RPAD, 512);
    gemm_mfma_x3<0><<<dim3(B_ / 64, 256 / 64), 256, 0, stream>>>(
        b1h, b1l, wt1h, wt1l, top_b1, buf2f, nullptr, nullptr, 512, 512, 512, 256);
    final_layer<<<B_ / 4, 256, 0, stream>>>(buf2f, top_W2, top_b2, out);
}